// Round 4
// baseline (54.508 us; speedup 1.0000x reference)
//
#include <hip/hip_runtime.h>
#include <cstdint>

// Problem constants
#define BB 8
#define LL 2048
#define DD 768
#define SS 512
#define MAXW 32

constexpr int M = BB * SS;   // 4096 spans
constexpr int K = 2 * DD;    // 1536
constexpr int N = DD;        // 768

typedef __attribute__((ext_vector_type(8))) short short8;   // 8 bf16 = 4 VGPRs
typedef __attribute__((ext_vector_type(4))) float f32x4;

__device__ __forceinline__ unsigned short f2bf(float f) {
    union { float f; unsigned int u; } v; v.f = f;
    unsigned int r = v.u + 0x7fffu + ((v.u >> 16) & 1u);  // RNE
    return (unsigned short)(r >> 16);
}
__device__ __forceinline__ float bf2f(unsigned short u) {
    union { unsigned int u; float f; } v; v.u = ((unsigned int)u) << 16;
    return v.f;
}

// generic -> addrspace casts for global_load_lds
#define AS1(p) reinterpret_cast<const __attribute__((address_space(1))) void*>( \
                   reinterpret_cast<uintptr_t>(p))
#define AS3(p) reinterpret_cast<__attribute__((address_space(3))) void*>( \
                   reinterpret_cast<uintptr_t>(p))

// ---------------------------------------------------------------------------
// Kernel 1 (fused): blocks [0,2048): repr f32 -> bf16, batch b = bid&7 so each
// batch's bf16 slice (3.07 MB < 4 MB) lands in XCD b's L2.
// Blocks [2048, 2048+1152): W_down (K x N f32) -> WT (N x K bf16) transpose.
// ---------------------------------------------------------------------------
__global__ __launch_bounds__(256) void prep_kernel(
    const float* __restrict__ repr,          // (B,L,D) f32
    unsigned short* __restrict__ reprb,      // (B,L,D) bf16
    const float* __restrict__ W,             // (K,N) f32
    unsigned short* __restrict__ WT)         // (N,K) bf16
{
    __shared__ float tbuf[32][33];
    const int bid = blockIdx.x;
    const int tid = threadIdx.x;

    if (bid < 2048) {
        const int b = bid & 7, c = bid >> 3;
        const size_t base = (size_t)b * (LL * DD) + (size_t)c * 6144;
        const float4* src = (const float4*)(repr + base);
        ushort4* dst = (ushort4*)(reprb + base);
        #pragma unroll
        for (int i = 0; i < 6; ++i) {
            const float4 v = src[i * 256 + tid];
            ushort4 o;
            o.x = f2bf(v.x); o.y = f2bf(v.y); o.z = f2bf(v.z); o.w = f2bf(v.w);
            dst[i * 256 + tid] = o;
        }
    } else {
        const int t = bid - 2048;
        const int n0 = (t % 24) * 32, k0 = (t / 24) * 32;
        const int tx = tid & 31, ty = tid >> 5;      // (32, 8)
        #pragma unroll
        for (int j = 0; j < 4; ++j)
            tbuf[ty + 8 * j][tx] = W[(size_t)(k0 + ty + 8 * j) * N + n0 + tx];
        __syncthreads();
        #pragma unroll
        for (int j = 0; j < 4; ++j)
            WT[(size_t)(n0 + ty + 8 * j) * K + k0 + tx] = f2bf(tbuf[tx][ty + 8 * j]);
    }
}

// ---------------------------------------------------------------------------
// Kernel 2: per-span masked max + mean over [start, end], bf16 repr from the
// batch-local XCD L2. bid&7 = batch -> XCD pin.
// ---------------------------------------------------------------------------
__global__ __launch_bounds__(192) void span_feat_kernel(
    const unsigned short* __restrict__ reprb,  // (B,L,D) bf16
    const int*   __restrict__ spans,           // (B,S,2) int
    unsigned short* __restrict__ cat)          // (M, 2D) bf16
{
    const int bid = blockIdx.x;
    const int b = bid & 7, s = bid >> 3;
    const int span = (b << 9) | s;
    const int t = threadIdx.x;                 // 0..191, 4 dims each

    const bool is64 = ((spans[1] | spans[3] | spans[5] | spans[7]) == 0);
    int st, en;
    if (is64) { st = spans[4 * span];     en = spans[4 * span + 2]; }
    else      { st = spans[2 * span];     en = spans[2 * span + 1]; }
    const int width = en - st;                 // 0..31, block-uniform

    const ushort4* base = (const ushort4*)reprb + (size_t)b * LL * (DD / 4);

    float4 mx = make_float4(-3.0e38f, -3.0e38f, -3.0e38f, -3.0e38f);
    float4 sm = make_float4(0.f, 0.f, 0.f, 0.f);

    for (int w = 0; w <= width; ++w) {
        const ushort4 u = base[(size_t)(en - w) * (DD / 4) + t];
        const float vx = bf2f(u.x), vy = bf2f(u.y), vz = bf2f(u.z), vw = bf2f(u.w);
        mx.x = fmaxf(mx.x, vx);  mx.y = fmaxf(mx.y, vy);
        mx.z = fmaxf(mx.z, vz);  mx.w = fmaxf(mx.w, vw);
        sm.x += vx;  sm.y += vy;  sm.z += vz;  sm.w += vw;
    }

    const float inv = 1.0f / (float)(width + 1);
    unsigned short* crow = cat + (size_t)span * K;
    ushort4 omax, omean;
    omax.x = f2bf(mx.x); omax.y = f2bf(mx.y); omax.z = f2bf(mx.z); omax.w = f2bf(mx.w);
    omean.x = f2bf(sm.x * inv); omean.y = f2bf(sm.y * inv);
    omean.z = f2bf(sm.z * inv); omean.w = f2bf(sm.w * inv);
    *(ushort4*)(crow + t * 4)      = omax;
    *(ushort4*)(crow + DD + t * 4) = omean;
}

// ---------------------------------------------------------------------------
// Kernel 3: out = cat(bf16) @ WT(bf16)^T + bias, MFMA 16x16x32.
// BM=128, BN=96, BK=64; 256 threads = 4 waves (2x2); wave tile 64x48.
// Double-buffered LDS + prefetch-before-compute (T3-min 2-phase):
//   STAGE(t+1 -> buf^1); compute(buf); __syncthreads (vmcnt drain); flip.
// grid 256 = 1 block/CU; bijective XCD swizzle -> per-XCD A panel 1.57 MB +
// full WT 2.4 MB ~ L2-resident.
// ---------------------------------------------------------------------------
constexpr int BM = 128, BN = 96, BK = 64;

__global__ __launch_bounds__(256) void gemm_bias_kernel(
    const unsigned short* __restrict__ A,    // (M, K)  bf16
    const unsigned short* __restrict__ WT,   // (N, K)  bf16
    const float* __restrict__ bias,          // (N)     f32
    float*       __restrict__ C)             // (M, N)  f32
{
    __shared__ unsigned short Asm[2][BM * BK];  // 2 x 16 KB, swizzled chunks
    __shared__ unsigned short Bsm[2][BN * BK];  // 2 x 12 KB

    const int tid = threadIdx.x;
    // XCD swizzle (256 % 8 == 0): XCD x gets 32 consecutive tiles ->
    // mt in [x*4, x*4+4), all 8 nt. A panel 1.57 MB + WT 2.4 MB per XCD.
    const int tile = (blockIdx.x & 7) * 32 + (blockIdx.x >> 3);
    const int mt = tile >> 3, nt = tile & 7;
    const int m0 = mt * BM, n0 = nt * BN;

    const int lane = tid & 63;
    const int wid  = tid >> 6;
    const int wm = wid >> 1, wn = wid & 1;   // 2x2 wave grid, wave tile 64x48
    const int lnib = lane & 15, hi = lane >> 4;

    f32x4 acc[4][3] = {};

    // ---- staging helper (A: 1024 chunks / 4 iters; B: 768 chunks / 3 iters)
    auto stage = [&](int k0, int buf) {
        #pragma unroll
        for (int it = 0; it < 4; ++it) {
            const int s   = it * 256 + tid;
            const int row = s >> 3, c8 = s & 7;
            const unsigned short* g =
                A + (size_t)(m0 + row) * K + k0 + ((c8 ^ (row & 7)) << 3);
            __builtin_amdgcn_global_load_lds(AS1(g), AS3(&Asm[buf][s << 3]), 16, 0, 0);
        }
        #pragma unroll
        for (int it = 0; it < 3; ++it) {
            const int s   = it * 256 + tid;
            const int row = s >> 3, c8 = s & 7;
            const unsigned short* g =
                WT + (size_t)(n0 + row) * K + k0 + ((c8 ^ (row & 7)) << 3);
            __builtin_amdgcn_global_load_lds(AS1(g), AS3(&Bsm[buf][s << 3]), 16, 0, 0);
        }
    };

    auto compute = [&](int buf) {
        #pragma unroll
        for (int kk = 0; kk < 2; ++kk) {
            short8 af[4], bf[3];
            const int cc = kk * 4 + hi;
            #pragma unroll
            for (int mf = 0; mf < 4; ++mf) {
                const int r = wm * 64 + mf * 16 + lnib;
                af[mf] = *(const short8*)&Asm[buf][(r * 8 + (cc ^ (r & 7))) << 3];
            }
            #pragma unroll
            for (int nf = 0; nf < 3; ++nf) {
                const int r = wn * 48 + nf * 16 + lnib;
                bf[nf] = *(const short8*)&Bsm[buf][(r * 8 + (cc ^ (r & 7))) << 3];
            }
            #pragma unroll
            for (int mf = 0; mf < 4; ++mf)
                #pragma unroll
                for (int nf = 0; nf < 3; ++nf)
                    acc[mf][nf] = __builtin_amdgcn_mfma_f32_16x16x32_bf16(
                        af[mf], bf[nf], acc[mf][nf], 0, 0, 0);
        }
    };

    constexpr int NT = K / BK;   // 24 K-steps

    stage(0, 0);
    __syncthreads();             // drains vmcnt(0): buf0 ready

    int cur = 0;
    #pragma unroll 1
    for (int t = 0; t < NT - 1; ++t) {
        stage((t + 1) * BK, cur ^ 1);  // issue next tile's loads first
        compute(cur);                   // MFMA on current while loads fly
        __syncthreads();                // vmcnt(0)+barrier: next buf ready,
        cur ^= 1;                       // and everyone done reading cur
    }
    compute(cur);                       // epilogue tile, no prefetch

    // Epilogue: bias + store. C/D: col = lane&15, row = hi*4 + reg.
    #pragma unroll
    for (int nf = 0; nf < 3; ++nf) {
        const int col = n0 + wn * 48 + nf * 16 + lnib;
        const float bv = bias[col];
        #pragma unroll
        for (int mf = 0; mf < 4; ++mf) {
            const int rbase = m0 + wm * 64 + mf * 16 + hi * 4;
            #pragma unroll
            for (int r = 0; r < 4; ++r)
                C[(size_t)(rbase + r) * N + col] = acc[mf][nf][r] + bv;
        }
    }
}

// ---------------------------------------------------------------------------
extern "C" void kernel_launch(void* const* d_in, const int* in_sizes, int n_in,
                              void* d_out, int out_size, void* d_ws, size_t ws_size,
                              hipStream_t stream)
{
    const float* repr  = (const float*)d_in[0];  // (B,L,D) f32
    const int*   spans = (const int*)  d_in[1];  // (B,S,2)
    const float* Wd    = (const float*)d_in[2];  // (2D,D) f32
    const float* bias  = (const float*)d_in[3];  // (D)    f32
    float* out = (float*)d_out;                  // (M, N) f32

    unsigned short* catb  = (unsigned short*)d_ws;            // M*K   = 12.6 MB
    unsigned short* WT    = catb + (size_t)M * K;             // N*K   =  2.4 MB
    unsigned short* reprb = WT   + (size_t)N * K;             // B*L*D = 25.2 MB

    prep_kernel<<<2048 + 1152, 256, 0, stream>>>(repr, reprb, Wd, WT);
    span_feat_kernel<<<M, 192, 0, stream>>>(reprb, spans, catb);
    gemm_bias_kernel<<<M / BM * (N / BN), 256, 0, stream>>>(catb, WT, bias, out);
}